// Round 1
// baseline (6490.195 us; speedup 1.0000x reference)
//
#include <hip/hip_runtime.h>
#include <math.h>

#define NN 256
#define TT 30
#define FF 128
#define NB 4

static constexpr float INV = 0.08838834764831845f; // 1/sqrt(128)

// ---------------------------------------------------------------------------
// gate_kernel: per (b,n): A = softmax(X X^T * inv) over s; gate[t] = A @ wlin
// grid (NN, NB), 128 threads
// ---------------------------------------------------------------------------
__global__ __launch_bounds__(128) void gate_kernel(
    const float* __restrict__ x, const float* __restrict__ wlin,
    float* __restrict__ gate) {
  int n = blockIdx.x, b = blockIdx.y;
  __shared__ float Xs[TT * 129];
  __shared__ float A[TT * 33];
  __shared__ float wl[TT];
  int tid = threadIdx.x;
  const float* xp = x + ((size_t)(b * NN + n)) * TT * FF;
  for (int idx = tid; idx < TT * FF; idx += 128) {
    int t = idx >> 7, f = idx & 127;
    Xs[t * 129 + f] = xp[idx];
  }
  if (tid < TT) wl[tid] = wlin[tid];
  __syncthreads();
  for (int p = tid; p < TT * TT; p += 128) {
    int t = p / TT, s = p - t * TT;
    float sum = 0.f;
    #pragma unroll 4
    for (int f = 0; f < FF; ++f) sum += Xs[t * 129 + f] * Xs[s * 129 + f];
    A[t * 33 + s] = sum * INV;
  }
  __syncthreads();
  if (tid < TT) {
    float mx = -1e30f;
    #pragma unroll
    for (int s = 0; s < TT; ++s) mx = fmaxf(mx, A[tid * 33 + s]);
    float e[TT];
    float sum = 0.f;
    #pragma unroll
    for (int s = 0; s < TT; ++s) {
      e[s] = expf(A[tid * 33 + s] - mx);
      sum += e[s];
    }
    float r = 1.f / sum;
    float g = 0.f;
    #pragma unroll
    for (int s = 0; s < TT; ++s) g += e[s] * wl[s];
    gate[((size_t)b * TT + tid) * NN + n] = g * r;
  }
}

// ---------------------------------------------------------------------------
// score_kernel:
//  mode 0 (iteration): S[n,m] = softmax_m(inv * <x[b,n,t], x[b,m,t+1]>)
//                      P[n,m] = phase[b,t+1,n,m] * S * gate[b,t+1,n]
//  mode 1 (final):     S[n,m] = softmax_m(inv * <x[b,n,t], x[b,m,t]>) * inv
//                      P[n,m] = phase[b,t,n,m] * sym_adj[n,m] * S
//  grid (4, T-1 or T, NB), 256 threads. Block owns 64 rows n, all 256 cols m.
//  Thread (tr,tc): rows n0+tr*4+r, cols m = j*16+tc.
// ---------------------------------------------------------------------------
__global__ __launch_bounds__(256) void score_kernel(
    const float* __restrict__ x, const float* __restrict__ phase,
    const float* __restrict__ gate, const float* __restrict__ symadj,
    float* __restrict__ P, int mode) {
  int ntile = blockIdx.x, t = blockIdx.y, b = blockIdx.z;
  int tq = t, tk = mode ? t : t + 1, pt = mode ? t : t + 1;
  __shared__ float Xn[64 * 36];   // 64 query rows, f-tile of 32 (+4 pad)
  __shared__ float Xm[256 * 36];  // all 256 key rows, f-tile of 32
  int tid = threadIdx.x;
  int tr = tid >> 4, tc = tid & 15;
  int n0 = ntile * 64;
  float acc[4][16];
  #pragma unroll
  for (int r = 0; r < 4; ++r)
    #pragma unroll
    for (int j = 0; j < 16; ++j) acc[r][j] = 0.f;

  for (int ftile = 0; ftile < 4; ++ftile) {
    __syncthreads();
    for (int idx = tid; idx < 256 * 8; idx += 256) {
      int row = idx >> 3, q = idx & 7;
      *(float4*)&Xm[row * 36 + q * 4] =
          *(const float4*)(x + (((size_t)(b * NN + row)) * TT + tk) * FF + ftile * 32 + q * 4);
    }
    for (int idx = tid; idx < 64 * 8; idx += 256) {
      int row = idx >> 3, q = idx & 7;
      *(float4*)&Xn[row * 36 + q * 4] =
          *(const float4*)(x + (((size_t)(b * NN + n0 + row)) * TT + tq) * FF + ftile * 32 + q * 4);
    }
    __syncthreads();
    #pragma unroll
    for (int f = 0; f < 32; f += 4) {
      float4 a0 = *(const float4*)&Xn[(tr * 4 + 0) * 36 + f];
      float4 a1 = *(const float4*)&Xn[(tr * 4 + 1) * 36 + f];
      float4 a2 = *(const float4*)&Xn[(tr * 4 + 2) * 36 + f];
      float4 a3 = *(const float4*)&Xn[(tr * 4 + 3) * 36 + f];
      #pragma unroll
      for (int j = 0; j < 16; ++j) {
        float4 bv = *(const float4*)&Xm[(j * 16 + tc) * 36 + f];
        acc[0][j] += a0.x * bv.x + a0.y * bv.y + a0.z * bv.z + a0.w * bv.w;
        acc[1][j] += a1.x * bv.x + a1.y * bv.y + a1.z * bv.z + a1.w * bv.w;
        acc[2][j] += a2.x * bv.x + a2.y * bv.y + a2.z * bv.z + a2.w * bv.w;
        acc[3][j] += a3.x * bv.x + a3.y * bv.y + a3.z * bv.z + a3.w * bv.w;
      }
    }
  }

  // softmax over m per row, then scale & store P
  #pragma unroll
  for (int r = 0; r < 4; ++r) {
    int n = n0 + tr * 4 + r;
    float mx = -1e30f;
    #pragma unroll
    for (int j = 0; j < 16; ++j) {
      acc[r][j] *= INV;
      mx = fmaxf(mx, acc[r][j]);
    }
    #pragma unroll
    for (int d = 1; d < 16; d <<= 1) mx = fmaxf(mx, __shfl_xor(mx, d));
    float sum = 0.f;
    #pragma unroll
    for (int j = 0; j < 16; ++j) {
      acc[r][j] = expf(acc[r][j] - mx);
      sum += acc[r][j];
    }
    #pragma unroll
    for (int d = 1; d < 16; d <<= 1) sum += __shfl_xor(sum, d);
    float rs = 1.f / sum;
    const float* prow = phase + (((size_t)(b * TT + pt)) * NN + n) * NN;
    float* orow = P + (((size_t)(b * TT + t)) * NN + n) * NN;
    if (mode == 0) {
      float g = gate[((size_t)b * TT + pt) * NN + n] * rs;
      #pragma unroll
      for (int j = 0; j < 16; ++j) {
        int m = j * 16 + tc;
        orow[m] = acc[r][j] * g * prow[m];
      }
    } else {
      float g = rs * INV;
      const float* srow = symadj + (size_t)n * NN;
      #pragma unroll
      for (int j = 0; j < 16; ++j) {
        int m = j * 16 + tc;
        orow[m] = acc[r][j] * g * prow[m] * srow[m];
      }
    }
  }
}

// ---------------------------------------------------------------------------
// pred_kernel: out[n,f] = sum_m P[m,n] * x[b,m,t,f]   (P^T X)
//  mode 0: write x_new[b,n,t+1,f] = mask ? x_old : pred ; t==0 copies slice 0
//  mode 1: write agg[b,t,n,f] = pred
//  grid (4, T-1 or T, NB), 256 threads. Thread (tr,tc): rows n0+tr*4+r,
//  f = q*16+tc (q<8).
// ---------------------------------------------------------------------------
__global__ __launch_bounds__(256) void pred_kernel(
    const float* __restrict__ x, const float* __restrict__ P,
    const int* __restrict__ mask, float* __restrict__ xout, int mode) {
  int ntile = blockIdx.x, t = blockIdx.y, b = blockIdx.z;
  __shared__ float Pt[64 * 64];
  __shared__ float Xt[64 * 128];
  int tid = threadIdx.x;
  int tr = tid >> 4, tc = tid & 15;
  int n0 = ntile * 64;
  float acc[4][8];
  #pragma unroll
  for (int r = 0; r < 4; ++r)
    #pragma unroll
    for (int q = 0; q < 8; ++q) acc[r][q] = 0.f;

  for (int mt = 0; mt < 4; ++mt) {
    __syncthreads();
    for (int idx = tid; idx < 64 * 16; idx += 256) {
      int row = idx >> 4, c4 = (idx & 15) * 4;
      *(float4*)&Pt[row * 64 + c4] =
          *(const float4*)(P + (((size_t)(b * TT + t)) * NN + mt * 64 + row) * NN + n0 + c4);
    }
    for (int idx = tid; idx < 64 * 32; idx += 256) {
      int row = idx >> 5, q = idx & 31;
      *(float4*)&Xt[row * 128 + q * 4] =
          *(const float4*)(x + (((size_t)(b * NN + mt * 64 + row)) * TT + t) * FF + q * 4);
    }
    __syncthreads();
    for (int i = 0; i < 64; ++i) {
      float4 pv = *(const float4*)&Pt[i * 64 + tr * 4];
      #pragma unroll
      for (int q = 0; q < 8; ++q) {
        float xv = Xt[i * 128 + q * 16 + tc];
        acc[0][q] += pv.x * xv;
        acc[1][q] += pv.y * xv;
        acc[2][q] += pv.z * xv;
        acc[3][q] += pv.w * xv;
      }
    }
  }

  if (mode == 0) {
    int tw = t + 1;
    #pragma unroll
    for (int r = 0; r < 4; ++r) {
      int n = n0 + tr * 4 + r;
      int mk = mask[n * TT + tw];
      const float* src = x + (((size_t)(b * NN + n)) * TT + tw) * FF;
      float* dst = xout + (((size_t)(b * NN + n)) * TT + tw) * FF;
      #pragma unroll
      for (int q = 0; q < 8; ++q) {
        int f = q * 16 + tc;
        dst[f] = mk ? src[f] : acc[r][q];
      }
    }
    if (t == 0) {
      #pragma unroll
      for (int r = 0; r < 4; ++r) {
        int n = n0 + tr * 4 + r;
        const float* src = x + (((size_t)(b * NN + n)) * TT) * FF;
        float* dst = xout + (((size_t)(b * NN + n)) * TT) * FF;
        #pragma unroll
        for (int q = 0; q < 8; ++q) {
          int f = q * 16 + tc;
          dst[f] = src[f];
        }
      }
    }
  } else {
    #pragma unroll
    for (int r = 0; r < 4; ++r) {
      int n = n0 + tr * 4 + r;
      float* dst = xout + (((size_t)(b * TT + t)) * NN + n) * FF;
      #pragma unroll
      for (int q = 0; q < 8; ++q) dst[q * 16 + tc] = acc[r][q];
    }
  }
}

// ---------------------------------------------------------------------------
// theta_kernel: out[b,n,t,o] = relu(sum_f agg[b,t,n,f] * Wt[o,f])
//  grid (4, T, NB), 256 threads
// ---------------------------------------------------------------------------
__global__ __launch_bounds__(256) void theta_kernel(
    const float* __restrict__ agg, const float* __restrict__ Wt,
    float* __restrict__ out) {
  int ntile = blockIdx.x, t = blockIdx.y, b = blockIdx.z;
  __shared__ float Ag[64 * 68];
  __shared__ float Ws[128 * 68];
  int tid = threadIdx.x;
  int tr = tid >> 4, tc = tid & 15;
  int n0 = ntile * 64;
  float acc[4][8];
  #pragma unroll
  for (int r = 0; r < 4; ++r)
    #pragma unroll
    for (int q = 0; q < 8; ++q) acc[r][q] = 0.f;

  for (int ft = 0; ft < 2; ++ft) {
    __syncthreads();
    for (int idx = tid; idx < 64 * 16; idx += 256) {
      int row = idx >> 4, c4 = (idx & 15) * 4;
      *(float4*)&Ag[row * 68 + c4] =
          *(const float4*)(agg + (((size_t)(b * TT + t)) * NN + n0 + row) * FF + ft * 64 + c4);
    }
    for (int idx = tid; idx < 128 * 16; idx += 256) {
      int row = idx >> 4, c4 = (idx & 15) * 4;
      *(float4*)&Ws[row * 68 + c4] =
          *(const float4*)(Wt + (size_t)row * FF + ft * 64 + c4);
    }
    __syncthreads();
    #pragma unroll
    for (int f = 0; f < 64; f += 4) {
      float4 a0 = *(const float4*)&Ag[(tr * 4 + 0) * 68 + f];
      float4 a1 = *(const float4*)&Ag[(tr * 4 + 1) * 68 + f];
      float4 a2 = *(const float4*)&Ag[(tr * 4 + 2) * 68 + f];
      float4 a3 = *(const float4*)&Ag[(tr * 4 + 3) * 68 + f];
      #pragma unroll
      for (int q = 0; q < 8; ++q) {
        float4 wv = *(const float4*)&Ws[(q * 16 + tc) * 68 + f];
        acc[0][q] += a0.x * wv.x + a0.y * wv.y + a0.z * wv.z + a0.w * wv.w;
        acc[1][q] += a1.x * wv.x + a1.y * wv.y + a1.z * wv.z + a1.w * wv.w;
        acc[2][q] += a2.x * wv.x + a2.y * wv.y + a2.z * wv.z + a2.w * wv.w;
        acc[3][q] += a3.x * wv.x + a3.y * wv.y + a3.z * wv.z + a3.w * wv.w;
      }
    }
  }

  #pragma unroll
  for (int r = 0; r < 4; ++r) {
    int n = n0 + tr * 4 + r;
    float* dst = out + (((size_t)(b * NN + n)) * TT + t) * FF;
    #pragma unroll
    for (int q = 0; q < 8; ++q) dst[q * 16 + tc] = fmaxf(acc[r][q], 0.f);
  }
}

// ---------------------------------------------------------------------------
extern "C" void kernel_launch(void* const* d_in, const int* in_sizes, int n_in,
                              void* d_out, int out_size, void* d_ws, size_t ws_size,
                              hipStream_t stream) {
  const float* x = (const float*)d_in[0];
  const float* phase = (const float*)d_in[1];
  const float* symadj = (const float*)d_in[2];
  const int* mask = (const int*)d_in[3];
  const float* Wt = (const float*)d_in[4];
  const float* Wl = (const float*)d_in[5];
  float* out = (float*)d_out;
  float* ws = (float*)d_ws;

  const size_t SX = (size_t)NB * NN * TT * FF;       // 3,932,160 floats
  float* xA = ws;
  float* xB = xA + SX;
  float* gateb = xB + SX;                            // NB*TT*NN floats
  float* Pw = gateb + (size_t)NB * TT * NN;          // NB*TT*NN*NN floats
  // agg reuses whichever x buffer is free after the loop

  hipMemcpyAsync(xA, x, SX * sizeof(float), hipMemcpyDeviceToDevice, stream);

  float* xc = xA;
  float* xn = xB;
  for (int it = 0; it < TT - 1; ++it) {
    gate_kernel<<<dim3(NN, NB), 128, 0, stream>>>(xc, Wl, gateb);
    score_kernel<<<dim3(4, TT - 1, NB), 256, 0, stream>>>(xc, phase, gateb, symadj, Pw, 0);
    pred_kernel<<<dim3(4, TT - 1, NB), 256, 0, stream>>>(xc, Pw, mask, xn, 0);
    float* tmp = xc; xc = xn; xn = tmp;
  }

  float* aggb = xn;  // free buffer
  score_kernel<<<dim3(4, TT, NB), 256, 0, stream>>>(xc, phase, nullptr, symadj, Pw, 1);
  pred_kernel<<<dim3(4, TT, NB), 256, 0, stream>>>(xc, Pw, nullptr, aggb, 1);
  theta_kernel<<<dim3(4, TT, NB), 256, 0, stream>>>(aggb, Wt, out);
}